// Round 1
// baseline (835.574 us; speedup 1.0000x reference)
//
#include <hip/hip_runtime.h>
#include <hip/hip_bf16.h>

#define EPS_LN 1e-5f

__device__ __forceinline__ float dot4(float4 a, float4 b) {
    return a.x * b.x + a.y * b.y + a.z * b.z + a.w * b.w;
}
__device__ __forceinline__ float sigmoidf_(float x) { return 1.0f / (1.0f + expf(-x)); }

__device__ __forceinline__ float bfu2f(unsigned short u) {
    unsigned v = ((unsigned)u) << 16;
    float f;
    __builtin_memcpy(&f, &v, 4);
    return f;
}
__device__ __forceinline__ unsigned short f2bfu(float f) {
    __hip_bfloat16 h = __float2bfloat16(f);
    unsigned short u;
    __builtin_memcpy(&u, &h, 2);
    return u;
}

// ---------------- lin0: out = relu(x @ lin0_w.T + b), h = out ----------------
__global__ void lin0_kernel(const float* __restrict__ x, const float* __restrict__ w,
                            const float* __restrict__ b, float* __restrict__ h, int N) {
    int id = blockIdx.x * blockDim.x + threadIdx.x;
    if (id >= N * 64) return;
    int n = id >> 6, o = id & 63;
    const float* xr = x + n * 16;
    const float* wr = w + o * 16;
    float acc = b[o];
#pragma unroll
    for (int k = 0; k < 16; k++) acc += xr[k] * wr[k];
    h[id] = fmaxf(acc, 0.0f);
}

// ---------------- in-degree counts ----------------
__global__ void count_kernel(const int* __restrict__ ei, float* __restrict__ counts, int E) {
    int e = blockIdx.x * blockDim.x + threadIdx.x;
    if (e < E) atomicAdd(&counts[ei[E + e]], 1.0f);
}

// ---------------- edge NN layer 1: e1 = relu(LN(ea @ W1.T + b1)) ----------------
__global__ __launch_bounds__(128) void edge_nn1_kernel(
    const float* __restrict__ ea, const float* __restrict__ w1, const float* __restrict__ b1,
    const float* __restrict__ g1, const float* __restrict__ b1n, float* __restrict__ e1, int E) {
    int e = blockIdx.x, j = threadIdx.x;
    float a0 = ea[e * 4 + 0], a1 = ea[e * 4 + 1], a2 = ea[e * 4 + 2], a3 = ea[e * 4 + 3];
    const float* wr = w1 + j * 4;
    float z = b1[j] + a0 * wr[0] + a1 * wr[1] + a2 * wr[2] + a3 * wr[3];
    float s = z, s2 = z * z;
#pragma unroll
    for (int m = 32; m >= 1; m >>= 1) { s += __shfl_xor(s, m); s2 += __shfl_xor(s2, m); }
    __shared__ float ls[2], ls2[2];
    int wv = j >> 6;
    if ((j & 63) == 0) { ls[wv] = s; ls2[wv] = s2; }
    __syncthreads();
    float S = ls[0] + ls[1], S2 = ls2[0] + ls2[1];
    float mu = S * (1.0f / 128.0f);
    float var = fmaxf(S2 * (1.0f / 128.0f) - mu * mu, 0.0f);
    float inv = rsqrtf(var + EPS_LN);
    float v = (z - mu) * inv * g1[j] + b1n[j];
    e1[e * 128 + j] = fmaxf(v, 0.0f);
}

// ---------------- z = e1 @ W2.T + b2, stored bf16 [E][4096] ----------------
// block: 16 edges x 512 outs; thread owns 2 out-cols x 16 edges
__global__ __launch_bounds__(256) void zgemm_kernel(
    const float* __restrict__ e1, const float* __restrict__ w2, const float* __restrict__ b2,
    unsigned short* __restrict__ z, int E) {
    const int t = threadIdx.x;
    const int eb = blockIdx.x * 16;
    const int o0 = blockIdx.y * 512 + t;
    const int o1 = o0 + 256;
    __shared__ __align__(16) float e1s[16][128];
#pragma unroll
    for (int i = 0; i < 2; i++) {
        int idx = t + i * 256;  // float4 index over 16*32
        int e = idx >> 5, k4 = idx & 31;
        *(float4*)&e1s[e][k4 * 4] = *(const float4*)&e1[(size_t)(eb + e) * 128 + k4 * 4];
    }
    __syncthreads();
    float acc0[16], acc1[16];
#pragma unroll
    for (int e = 0; e < 16; e++) { acc0[e] = 0.f; acc1[e] = 0.f; }
    const float4* w0p = (const float4*)(w2 + (size_t)o0 * 128);
    const float4* w1p = (const float4*)(w2 + (size_t)o1 * 128);
#pragma unroll 4
    for (int k4 = 0; k4 < 32; k4++) {
        float4 wa = w0p[k4], wb = w1p[k4];
#pragma unroll
        for (int e = 0; e < 16; e++) {
            float4 a = *(const float4*)&e1s[e][k4 * 4];
            acc0[e] += dot4(a, wa);
            acc1[e] += dot4(a, wb);
        }
    }
    float bb0 = b2[o0], bb1 = b2[o1];
#pragma unroll
    for (int e = 0; e < 16; e++) {
        z[(size_t)(eb + e) * 4096 + o0] = f2bfu(acc0[e] + bb0);
        z[(size_t)(eb + e) * 4096 + o1] = f2bfu(acc1[e] + bb1);
    }
}

// ---------------- per-edge LN over 4096, in place, -> ew (bf16) ----------------
__global__ __launch_bounds__(256) void ln_ew_kernel(unsigned short* __restrict__ z,
                                                    const float* __restrict__ g2,
                                                    const float* __restrict__ b2n) {
    int e = blockIdx.x, t = threadIdx.x;
    unsigned short* row = z + (size_t)e * 4096;
    float vals[16];
    float s = 0.f, s2 = 0.f;
#pragma unroll
    for (int c = 0; c < 4; c++) {
        ushort4 u = ((const ushort4*)row)[t + c * 256];
        float f0 = bfu2f(u.x), f1 = bfu2f(u.y), f2 = bfu2f(u.z), f3 = bfu2f(u.w);
        vals[c * 4 + 0] = f0; vals[c * 4 + 1] = f1; vals[c * 4 + 2] = f2; vals[c * 4 + 3] = f3;
        s += f0 + f1 + f2 + f3;
        s2 += f0 * f0 + f1 * f1 + f2 * f2 + f3 * f3;
    }
#pragma unroll
    for (int m = 32; m >= 1; m >>= 1) { s += __shfl_xor(s, m); s2 += __shfl_xor(s2, m); }
    __shared__ float red[8];
    if ((t & 63) == 0) { red[t >> 6] = s; red[4 + (t >> 6)] = s2; }
    __syncthreads();
    s = red[0] + red[1] + red[2] + red[3];
    s2 = red[4] + red[5] + red[6] + red[7];
    float mu = s * (1.0f / 4096.0f);
    float var = fmaxf(s2 * (1.0f / 4096.0f) - mu * mu, 0.0f);
    float inv = rsqrtf(var + EPS_LN);
#pragma unroll
    for (int c = 0; c < 4; c++) {
        int f = (t + c * 256) * 4;
        ushort4 u;
        u.x = f2bfu((vals[c * 4 + 0] - mu) * inv * g2[f + 0] + b2n[f + 0]);
        u.y = f2bfu((vals[c * 4 + 1] - mu) * inv * g2[f + 1] + b2n[f + 1]);
        u.z = f2bfu((vals[c * 4 + 2] - mu) * inv * g2[f + 2] + b2n[f + 2]);
        u.w = f2bfu((vals[c * 4 + 3] - mu) * inv * g2[f + 3] + b2n[f + 3]);
        ((ushort4*)row)[t + c * 256] = u;
    }
}

// ---------------- msg[e][o] = sum_d h[src][d]*ew[e][d][o]; scatter to agg ----------------
__global__ __launch_bounds__(256) void msg_kernel(const unsigned short* __restrict__ ew,
                                                  const float* __restrict__ h,
                                                  const int* __restrict__ ei,
                                                  float* __restrict__ agg, int E) {
    int t = threadIdx.x;
    int el = t >> 6, o = t & 63;
    int e = blockIdx.x * 4 + el;
    __shared__ float sL[4][64];
    int src = ei[e];
    int dstn = ei[E + e];
    sL[el][o] = h[src * 64 + o];
    __syncthreads();
    float acc = 0.f;
    const unsigned short* er = ew + (size_t)e * 4096 + o;
#pragma unroll 8
    for (int d = 0; d < 64; d++) acc += bfu2f(er[d * 64]) * sL[el][d];
    atomicAdd(&agg[dstn * 64 + o], acc);
}

// ---------------- GRU cell over 8 nodes/block ----------------
__global__ __launch_bounds__(192) void gru_kernel(
    const float* __restrict__ agg, const float* __restrict__ counts, const float* __restrict__ cbias,
    const float* __restrict__ wih, const float* __restrict__ whh,
    const float* __restrict__ bih, const float* __restrict__ bhh, float* __restrict__ h, int N) {
    int t = threadIdx.x;
    int nb = blockIdx.x * 8;
    __shared__ __align__(16) float mL[8][64], hL[8][64], gxL[8][192], ghL[8][192];
    for (int idx = t; idx < 512; idx += 192) {
        int n = idx >> 6, k = idx & 63;
        int node = nb + n;
        float cnt = fmaxf(counts[node], 1.0f);
        mL[n][k] = fmaxf(agg[node * 64 + k] / cnt + cbias[k], 0.0f);
        hL[n][k] = h[node * 64 + k];
    }
    __syncthreads();
    {
        int j = t;  // 0..191
        float ax[8], ah[8];
#pragma unroll
        for (int n = 0; n < 8; n++) { ax[n] = 0.f; ah[n] = 0.f; }
        const float4* wi = (const float4*)(wih + j * 64);
        const float4* wh = (const float4*)(whh + j * 64);
#pragma unroll 4
        for (int k4 = 0; k4 < 16; k4++) {
            float4 wiv = wi[k4], whv = wh[k4];
#pragma unroll
            for (int n = 0; n < 8; n++) {
                ax[n] += dot4(wiv, *(const float4*)&mL[n][k4 * 4]);
                ah[n] += dot4(whv, *(const float4*)&hL[n][k4 * 4]);
            }
        }
        float bi = bih[j], bh = bhh[j];
#pragma unroll
        for (int n = 0; n < 8; n++) { gxL[n][j] = ax[n] + bi; ghL[n][j] = ah[n] + bh; }
    }
    __syncthreads();
    for (int idx = t; idx < 512; idx += 192) {
        int n = idx >> 6, k = idx & 63;
        int node = nb + n;
        float r = sigmoidf_(gxL[n][k] + ghL[n][k]);
        float zz = sigmoidf_(gxL[n][64 + k] + ghL[n][64 + k]);
        float nn = tanhf(gxL[n][128 + k] + r * ghL[n][128 + k]);
        h[node * 64 + k] = (1.0f - zz) * nn + zz * hL[n][k];
    }
}

// ---------------- Set2Set prep ----------------
__global__ void prep_wc_kernel(const float* __restrict__ wih, const float* __restrict__ whh,
                               const float* __restrict__ bih, const float* __restrict__ bhh,
                               float* __restrict__ wc, float* __restrict__ bsum) {
    int id = blockIdx.x * 256 + threadIdx.x;
    if (id < 16384) {
        int j = id >> 6, k = id & 63;
        wc[id] = wih[j * 128 + k] + whh[id];
    }
    if (id < 256) bsum[id] = bih[id] + bhh[id];
}

// c_out[n][j] = sum_k out[n][k] * lstm_w_ih[j][64+k]
__global__ __launch_bounds__(256) void cout_kernel(const float* __restrict__ h,
                                                   const float* __restrict__ wih,
                                                   float* __restrict__ cout, int N) {
    int t = threadIdx.x, nb = blockIdx.x * 8;
    __shared__ __align__(16) float oL[8][64];
    for (int idx = t; idx < 512; idx += 256) {
        int n = idx >> 6, k = idx & 63;
        oL[n][k] = h[(nb + n) * 64 + k];
    }
    __syncthreads();
    int j = t;
    float acc[8];
#pragma unroll
    for (int n = 0; n < 8; n++) acc[n] = 0.f;
    const float* wr = wih + j * 128 + 64;
#pragma unroll 4
    for (int k4 = 0; k4 < 16; k4++) {
        float4 w4 = *(const float4*)&wr[k4 * 4];
#pragma unroll
        for (int n = 0; n < 8; n++) acc[n] += dot4(w4, *(const float4*)&oL[n][k4 * 4]);
    }
#pragma unroll
    for (int n = 0; n < 8; n++) cout[(size_t)(nb + n) * 256 + j] = acc[n];
}

// LSTM step 1: all inputs zero -> g = b_ih + b_hh
__global__ void lstm_init_kernel(const float* __restrict__ bsum, float* __restrict__ hl,
                                 float* __restrict__ cl, int N) {
    int id = blockIdx.x * 256 + threadIdx.x;
    if (id >= N * 64) return;
    int j = id & 63;
    float gi = bsum[j], gg = bsum[128 + j], go = bsum[192 + j];
    float c = sigmoidf_(gi) * tanhf(gg);
    cl[id] = c;
    hl[id] = sigmoidf_(go) * tanhf(c);
}

// LSTM steps 2,3: g = hl @ Wc.T + c_out + bsum
__global__ __launch_bounds__(256) void lstm_step_kernel(const float* __restrict__ wc,
                                                        const float* __restrict__ bsum,
                                                        const float* __restrict__ cout,
                                                        float* __restrict__ hl,
                                                        float* __restrict__ cl, int N) {
    int t = threadIdx.x, nb = blockIdx.x * 8;
    __shared__ __align__(16) float hlL[8][64];
    __shared__ float gL[8][256];
    for (int idx = t; idx < 512; idx += 256) {
        int n = idx >> 6, k = idx & 63;
        hlL[n][k] = hl[(nb + n) * 64 + k];
    }
    __syncthreads();
    {
        int j = t;
        float acc[8];
#pragma unroll
        for (int n = 0; n < 8; n++) acc[n] = 0.f;
        const float4* w4p = (const float4*)(wc + j * 64);
#pragma unroll 4
        for (int k4 = 0; k4 < 16; k4++) {
            float4 w4 = w4p[k4];
#pragma unroll
            for (int n = 0; n < 8; n++) acc[n] += dot4(w4, *(const float4*)&hlL[n][k4 * 4]);
        }
        float bs = bsum[j];
#pragma unroll
        for (int n = 0; n < 8; n++) gL[n][j] = acc[n] + cout[(size_t)(nb + n) * 256 + j] + bs;
    }
    __syncthreads();
    for (int idx = t; idx < 512; idx += 256) {
        int n = idx >> 6, k = idx & 63;
        int node = nb + n;
        float gi = gL[n][k], gf = gL[n][64 + k], gg = gL[n][128 + k], go = gL[n][192 + k];
        float c = sigmoidf_(gf) * cl[node * 64 + k] + sigmoidf_(gi) * tanhf(gg);
        cl[node * 64 + k] = c;
        hl[node * 64 + k] = sigmoidf_(go) * tanhf(c);
    }
}

// ---------------- head: 4 pairs/block, wave per pair ----------------
__global__ __launch_bounds__(256) void head_kernel(
    const float* __restrict__ h, const float* __restrict__ hl, const int* __restrict__ ti,
    const int* __restrict__ tc, const float* __restrict__ w1, const float* __restrict__ b1,
    const float* __restrict__ g1, const float* __restrict__ bn1, const float* __restrict__ w2,
    const float* __restrict__ b2, float* __restrict__ out, int P) {
    int t = threadIdx.x;
    int pb = blockIdx.x * 4;
    int pl = t >> 6, j = t & 63;
    __shared__ __align__(16) float st[4][4][64];  // [arr: oa0,oa1,ha0,ha1][pair][k]
    for (int idx = t; idx < 1024; idx += 256) {
        int arr = idx >> 8, p = (idx >> 6) & 3, k = idx & 63;
        int pair = pb + p;
        int a0 = ti[pair], a1 = ti[P + pair];
        float v;
        if (arr == 0) v = h[a0 * 64 + k];
        else if (arr == 1) v = h[a1 * 64 + k];
        else if (arr == 2) v = hl[a0 * 64 + k];
        else v = hl[a1 * 64 + k];
        st[arr][p][k] = v;
    }
    __syncthreads();
    int pair = pb + pl;
    float acc = b1[j];
    const float4* w = (const float4*)(w1 + (size_t)j * 384);
    // cat segments -> staged array: [oa0, oa1, ha0, oa0, ha1, oa1]
    const int segarr[6] = {0, 1, 2, 0, 3, 1};
#pragma unroll
    for (int s = 0; s < 6; s++) {
        int arr = segarr[s];
#pragma unroll
        for (int k4 = 0; k4 < 16; k4++)
            acc += dot4(w[s * 16 + k4], *(const float4*)&st[arr][pl][k4 * 4]);
    }
    float s1 = acc, s2v = acc * acc;
#pragma unroll
    for (int m = 32; m >= 1; m >>= 1) { s1 += __shfl_xor(s1, m); s2v += __shfl_xor(s2v, m); }
    float mu = s1 * (1.0f / 64.0f);
    float var = fmaxf(s2v * (1.0f / 64.0f) - mu * mu, 0.0f);
    float p1 = fmaxf((acc - mu) * rsqrtf(var + EPS_LN) * g1[j] + bn1[j], 0.0f);
    int cls = tc[pair];
    float part = p1 * w2[cls * 64 + j];
#pragma unroll
    for (int m = 32; m >= 1; m >>= 1) part += __shfl_xor(part, m);
    if (j == 0) out[pair] = part + b2[cls];
}

extern "C" void kernel_launch(void* const* d_in, const int* in_sizes, int n_in,
                              void* d_out, int out_size, void* d_ws, size_t ws_size,
                              hipStream_t stream) {
    const float* x = (const float*)d_in[0];
    const float* edge_attr = (const float*)d_in[1];
    const float* lin0_w = (const float*)d_in[2];
    const float* lin0_b = (const float*)d_in[3];
    const float* enn_w1 = (const float*)d_in[4];
    const float* enn_b1 = (const float*)d_in[5];
    const float* enn_g1 = (const float*)d_in[6];
    const float* enn_b1n = (const float*)d_in[7];
    const float* enn_w2 = (const float*)d_in[8];
    const float* enn_b2 = (const float*)d_in[9];
    const float* enn_g2 = (const float*)d_in[10];
    const float* enn_b2n = (const float*)d_in[11];
    const float* conv_bias = (const float*)d_in[12];
    const float* gru_w_ih = (const float*)d_in[13];
    const float* gru_w_hh = (const float*)d_in[14];
    const float* gru_b_ih = (const float*)d_in[15];
    const float* gru_b_hh = (const float*)d_in[16];
    const float* lstm_w_ih = (const float*)d_in[17];
    const float* lstm_w_hh = (const float*)d_in[18];
    const float* lstm_b_ih = (const float*)d_in[19];
    const float* lstm_b_hh = (const float*)d_in[20];
    const float* lin1_w = (const float*)d_in[21];
    const float* lin1_b = (const float*)d_in[22];
    const float* lin1_g = (const float*)d_in[23];
    const float* lin1_bn = (const float*)d_in[24];
    const float* lin2_w = (const float*)d_in[25];
    const float* lin2_b = (const float*)d_in[26];
    const int* edge_index = (const int*)d_in[27];
    const int* target_index = (const int*)d_in[28];
    const int* target_class = (const int*)d_in[29];

    const int N = in_sizes[0] / 16;
    const int E = in_sizes[27] / 2;
    const int P = in_sizes[29];

    // workspace carve
    size_t off = 0;
    auto carve = [&](size_t bytes) {
        void* p = (char*)d_ws + off;
        off += (bytes + 255) & ~(size_t)255;
        return p;
    };
    unsigned short* zbuf = (unsigned short*)carve((size_t)E * 4096 * 2);  // z then ew (bf16)
    float* e1 = (float*)carve((size_t)E * 128 * 4);
    float* hbuf = (float*)carve((size_t)N * 64 * 4);
    float* agg = (float*)carve((size_t)N * 64 * 4);
    float* counts = (float*)carve((size_t)N * 4);
    float* hl = (float*)carve((size_t)N * 64 * 4);
    float* cl = (float*)carve((size_t)N * 64 * 4);
    float* cout_b = (float*)carve((size_t)N * 256 * 4);
    float* wc = (float*)carve((size_t)256 * 64 * 4);
    float* bsum = (float*)carve((size_t)256 * 4);
    (void)ws_size;

    hipMemsetAsync(counts, 0, (size_t)N * 4, stream);
    lin0_kernel<<<(N * 64 + 255) / 256, 256, 0, stream>>>(x, lin0_w, lin0_b, hbuf, N);
    count_kernel<<<(E + 255) / 256, 256, 0, stream>>>(edge_index, counts, E);
    edge_nn1_kernel<<<E, 128, 0, stream>>>(edge_attr, enn_w1, enn_b1, enn_g1, enn_b1n, e1, E);
    {
        dim3 g(E / 16, 8);
        zgemm_kernel<<<g, 256, 0, stream>>>(e1, enn_w2, enn_b2, zbuf, E);
    }
    ln_ew_kernel<<<E, 256, 0, stream>>>(zbuf, enn_g2, enn_b2n);

    for (int it = 0; it < 3; it++) {
        hipMemsetAsync(agg, 0, (size_t)N * 64 * 4, stream);
        msg_kernel<<<E / 4, 256, 0, stream>>>(zbuf, hbuf, edge_index, agg, E);
        gru_kernel<<<N / 8, 192, 0, stream>>>(agg, counts, conv_bias, gru_w_ih, gru_w_hh,
                                              gru_b_ih, gru_b_hh, hbuf, N);
    }

    prep_wc_kernel<<<64, 256, 0, stream>>>(lstm_w_ih, lstm_w_hh, lstm_b_ih, lstm_b_hh, wc, bsum);
    cout_kernel<<<N / 8, 256, 0, stream>>>(hbuf, lstm_w_ih, cout_b, N);
    lstm_init_kernel<<<(N * 64 + 255) / 256, 256, 0, stream>>>(bsum, hl, cl, N);
    lstm_step_kernel<<<N / 8, 256, 0, stream>>>(wc, bsum, cout_b, hl, cl, N);
    lstm_step_kernel<<<N / 8, 256, 0, stream>>>(wc, bsum, cout_b, hl, cl, N);

    head_kernel<<<P / 4, 256, 0, stream>>>(hbuf, hl, target_index, target_class, lin1_w, lin1_b,
                                           lin1_g, lin1_bn, lin2_w, lin2_b, (float*)d_out, P);
}

// Round 2
// 531.410 us; speedup vs baseline: 1.5724x; 1.5724x over previous
//
#include <hip/hip_runtime.h>
#include <hip/hip_bf16.h>

#define EPS_LN 1e-5f

typedef __attribute__((ext_vector_type(8))) short bf16x8;
typedef __attribute__((ext_vector_type(4))) float f32x4;

__device__ __forceinline__ float dot4(float4 a, float4 b) {
    return a.x * b.x + a.y * b.y + a.z * b.z + a.w * b.w;
}
__device__ __forceinline__ float sigmoidf_(float x) { return 1.0f / (1.0f + expf(-x)); }

__device__ __forceinline__ float bfu2f(unsigned short u) {
    unsigned v = ((unsigned)u) << 16;
    float f;
    __builtin_memcpy(&f, &v, 4);
    return f;
}
__device__ __forceinline__ unsigned short f2bfu(float f) {
    __hip_bfloat16 h = __float2bfloat16(f);
    unsigned short u;
    __builtin_memcpy(&u, &h, 2);
    return u;
}

// ---------------- lin0: out = relu(x @ lin0_w.T + b), h = out ----------------
__global__ void lin0_kernel(const float* __restrict__ x, const float* __restrict__ w,
                            const float* __restrict__ b, float* __restrict__ h, int N) {
    int id = blockIdx.x * blockDim.x + threadIdx.x;
    if (id >= N * 64) return;
    int n = id >> 6, o = id & 63;
    const float* xr = x + n * 16;
    const float* wr = w + o * 16;
    float acc = b[o];
#pragma unroll
    for (int k = 0; k < 16; k++) acc += xr[k] * wr[k];
    h[id] = fmaxf(acc, 0.0f);
}

// ---------------- in-degree counts ----------------
__global__ void count_kernel(const int* __restrict__ ei, float* __restrict__ counts, int E) {
    int e = blockIdx.x * blockDim.x + threadIdx.x;
    if (e < E) atomicAdd(&counts[ei[E + e]], 1.0f);
}

// ---------------- W2 fp32 -> bf16 ----------------
__global__ void w2cvt_kernel(const float* __restrict__ w2, unsigned short* __restrict__ w2b, int n) {
    int id = blockIdx.x * blockDim.x + threadIdx.x;
    if (id < n) w2b[id] = f2bfu(w2[id]);
}

// ---------------- edge NN layer 1: e1 = relu(LN(ea @ W1.T + b1)), split hi/lo bf16 ----------------
__global__ __launch_bounds__(128) void edge_nn1_kernel(
    const float* __restrict__ ea, const float* __restrict__ w1, const float* __restrict__ b1,
    const float* __restrict__ g1, const float* __restrict__ b1n,
    unsigned short* __restrict__ e1h, unsigned short* __restrict__ e1l, int E) {
    int e = blockIdx.x, j = threadIdx.x;
    float a0 = ea[e * 4 + 0], a1 = ea[e * 4 + 1], a2 = ea[e * 4 + 2], a3 = ea[e * 4 + 3];
    const float* wr = w1 + j * 4;
    float z = b1[j] + a0 * wr[0] + a1 * wr[1] + a2 * wr[2] + a3 * wr[3];
    float s = z, s2 = z * z;
#pragma unroll
    for (int m = 32; m >= 1; m >>= 1) { s += __shfl_xor(s, m); s2 += __shfl_xor(s2, m); }
    __shared__ float ls[2], ls2[2];
    int wv = j >> 6;
    if ((j & 63) == 0) { ls[wv] = s; ls2[wv] = s2; }
    __syncthreads();
    float S = ls[0] + ls[1], S2 = ls2[0] + ls2[1];
    float mu = S * (1.0f / 128.0f);
    float var = fmaxf(S2 * (1.0f / 128.0f) - mu * mu, 0.0f);
    float inv = rsqrtf(var + EPS_LN);
    float v = fmaxf((z - mu) * inv * g1[j] + b1n[j], 0.0f);
    unsigned short hi = f2bfu(v);
    unsigned short lo = f2bfu(v - bfu2f(hi));
    e1h[e * 128 + j] = hi;
    e1l[e * 128 + j] = lo;
}

// ---------------- z = e1 @ W2.T + b2 via MFMA (2-pass hi/lo), stored bf16 [E][4096] ----
// tile: 64 edges x 128 cols, K=128 fully staged. 4 waves of 32x64.
// LDS: A_hi[64][128]bf16 @0 (16K), A_lo @16K, B[128][128]bf16 @32K (32K). 64KB total.
// XOR swizzle on k-byte-offset: off ^ ((row&7)<<4)  (both write and read sides).
__global__ __launch_bounds__(256) void zgemm_mfma(
    const unsigned short* __restrict__ e1h, const unsigned short* __restrict__ e1l,
    const unsigned short* __restrict__ w2b, const float* __restrict__ b2,
    unsigned short* __restrict__ z, int E) {
    __shared__ __align__(16) unsigned char smem[65536];
    const int t = threadIdx.x;
    const int eb = blockIdx.x * 64;
    const int cb = blockIdx.y * 128;

    // ---- stage A_hi, A_lo (64 rows x 16 k-segs of 16B) ----
#pragma unroll
    for (int r = 0; r < 4; r++) {
        int idx = t + r * 256;
        int row = idx >> 4, kseg = idx & 15;
        int er = eb + row;
        if (er >= E) er = E - 1;
        uint4 vh = *(const uint4*)&e1h[(size_t)er * 128 + kseg * 8];
        uint4 vl = *(const uint4*)&e1l[(size_t)er * 128 + kseg * 8];
        int off = row * 256 + ((kseg * 16) ^ ((row & 7) << 4));
        *(uint4*)(smem + off) = vh;
        *(uint4*)(smem + 16384 + off) = vl;
    }
    // ---- stage B (128 rows x 16 k-segs) ----
#pragma unroll
    for (int r = 0; r < 8; r++) {
        int idx = t + r * 256;
        int row = idx >> 4, kseg = idx & 15;
        uint4 v = *(const uint4*)&w2b[(size_t)(cb + row) * 128 + kseg * 8];
        int off = row * 256 + ((kseg * 16) ^ ((row & 7) << 4));
        *(uint4*)(smem + 32768 + off) = v;
    }
    __syncthreads();

    const int w = t >> 6, lane = t & 63;
    const int wrow = (w >> 1) * 32;   // 0 or 32
    const int wcol = (w & 1) * 64;    // 0 or 64
    const int r16 = lane & 15, kg = lane >> 4;

    // preload all B fragments: b[nj][ks]
    bf16x8 bfrag[4][4];
#pragma unroll
    for (int nj = 0; nj < 4; nj++) {
#pragma unroll
        for (int ks = 0; ks < 4; ks++) {
            int row = wcol + nj * 16 + r16;
            int koff = ks * 64 + kg * 16;
            bfrag[nj][ks] = *(const bf16x8*)(smem + 32768 + row * 256 + (koff ^ ((row & 7) << 4)));
        }
    }
    f32x4 acc[2][4];
#pragma unroll
    for (int mi = 0; mi < 2; mi++)
#pragma unroll
        for (int nj = 0; nj < 4; nj++) acc[mi][nj] = (f32x4){0.f, 0.f, 0.f, 0.f};

#pragma unroll
    for (int pass = 0; pass < 2; pass++) {
        int abase = pass * 16384;
#pragma unroll
        for (int ks = 0; ks < 4; ks++) {
            bf16x8 afrag[2];
#pragma unroll
            for (int mi = 0; mi < 2; mi++) {
                int row = wrow + mi * 16 + r16;
                int koff = ks * 64 + kg * 16;
                afrag[mi] = *(const bf16x8*)(smem + abase + row * 256 + (koff ^ ((row & 7) << 4)));
            }
#pragma unroll
            for (int mi = 0; mi < 2; mi++)
#pragma unroll
                for (int nj = 0; nj < 4; nj++)
                    acc[mi][nj] = __builtin_amdgcn_mfma_f32_16x16x32_bf16(
                        afrag[mi], bfrag[nj][ks], acc[mi][nj], 0, 0, 0);
        }
    }

    // bias per output col
    float bb[4];
#pragma unroll
    for (int nj = 0; nj < 4; nj++) bb[nj] = b2[cb + wcol + nj * 16 + r16];

    // ---- transpose through LDS for coalesced bf16 stores ----
    __syncthreads();  // staging reads done; reuse smem
    // zT layout: [64 rows][stride 272 bytes]
#pragma unroll
    for (int mi = 0; mi < 2; mi++)
#pragma unroll
        for (int nj = 0; nj < 4; nj++)
#pragma unroll
            for (int r = 0; r < 4; r++) {
                int row = wrow + mi * 16 + (lane >> 4) * 4 + r;
                int col = wcol + nj * 16 + r16;
                *(unsigned short*)(smem + row * 272 + col * 2) = f2bfu(acc[mi][nj][r] + bb[nj]);
            }
    __syncthreads();
#pragma unroll
    for (int r = 0; r < 4; r++) {
        int idx = t + r * 256;
        int row = idx >> 4, seg = idx & 15;
        if (eb + row < E) {
            uint4 v = *(const uint4*)(smem + row * 272 + seg * 16);
            *(uint4*)&z[(size_t)(eb + row) * 4096 + cb + seg * 8] = v;
        }
    }
}

// ---------------- per-edge LN over 4096, in place, -> ew (bf16) ----------------
__global__ __launch_bounds__(256) void ln_ew_kernel(unsigned short* __restrict__ z,
                                                    const float* __restrict__ g2,
                                                    const float* __restrict__ b2n) {
    int e = blockIdx.x, t = threadIdx.x;
    unsigned short* row = z + (size_t)e * 4096;
    float vals[16];
    float s = 0.f, s2 = 0.f;
#pragma unroll
    for (int c = 0; c < 4; c++) {
        ushort4 u = ((const ushort4*)row)[t + c * 256];
        float f0 = bfu2f(u.x), f1 = bfu2f(u.y), f2 = bfu2f(u.z), f3 = bfu2f(u.w);
        vals[c * 4 + 0] = f0; vals[c * 4 + 1] = f1; vals[c * 4 + 2] = f2; vals[c * 4 + 3] = f3;
        s += f0 + f1 + f2 + f3;
        s2 += f0 * f0 + f1 * f1 + f2 * f2 + f3 * f3;
    }
#pragma unroll
    for (int m = 32; m >= 1; m >>= 1) { s += __shfl_xor(s, m); s2 += __shfl_xor(s2, m); }
    __shared__ float red[8];
    if ((t & 63) == 0) { red[t >> 6] = s; red[4 + (t >> 6)] = s2; }
    __syncthreads();
    s = red[0] + red[1] + red[2] + red[3];
    s2 = red[4] + red[5] + red[6] + red[7];
    float mu = s * (1.0f / 4096.0f);
    float var = fmaxf(s2 * (1.0f / 4096.0f) - mu * mu, 0.0f);
    float inv = rsqrtf(var + EPS_LN);
#pragma unroll
    for (int c = 0; c < 4; c++) {
        int f = (t + c * 256) * 4;
        ushort4 u;
        u.x = f2bfu((vals[c * 4 + 0] - mu) * inv * g2[f + 0] + b2n[f + 0]);
        u.y = f2bfu((vals[c * 4 + 1] - mu) * inv * g2[f + 1] + b2n[f + 1]);
        u.z = f2bfu((vals[c * 4 + 2] - mu) * inv * g2[f + 2] + b2n[f + 2]);
        u.w = f2bfu((vals[c * 4 + 3] - mu) * inv * g2[f + 3] + b2n[f + 3]);
        ((ushort4*)row)[t + c * 256] = u;
    }
}

// ---------------- msg[e][o] = sum_d h[src][d]*ew[e][d][o]; scatter to agg ----------------
__global__ __launch_bounds__(256) void msg_kernel(const unsigned short* __restrict__ ew,
                                                  const float* __restrict__ h,
                                                  const int* __restrict__ ei,
                                                  float* __restrict__ agg, int E) {
    int t = threadIdx.x;
    int el = t >> 6, o = t & 63;
    int e = blockIdx.x * 4 + el;
    __shared__ float sL[4][64];
    int src = ei[e];
    int dstn = ei[E + e];
    sL[el][o] = h[src * 64 + o];
    __syncthreads();
    float acc = 0.f;
    const unsigned short* er = ew + (size_t)e * 4096 + o;
#pragma unroll 8
    for (int d = 0; d < 64; d++) acc += bfu2f(er[d * 64]) * sL[el][d];
    atomicAdd(&agg[dstn * 64 + o], acc);
}

// ---------------- GRU cell over 8 nodes/block ----------------
__global__ __launch_bounds__(192) void gru_kernel(
    const float* __restrict__ agg, const float* __restrict__ counts, const float* __restrict__ cbias,
    const float* __restrict__ wih, const float* __restrict__ whh,
    const float* __restrict__ bih, const float* __restrict__ bhh, float* __restrict__ h, int N) {
    int t = threadIdx.x;
    int nb = blockIdx.x * 8;
    __shared__ __align__(16) float mL[8][64], hL[8][64], gxL[8][192], ghL[8][192];
    for (int idx = t; idx < 512; idx += 192) {
        int n = idx >> 6, k = idx & 63;
        int node = nb + n;
        float cnt = fmaxf(counts[node], 1.0f);
        mL[n][k] = fmaxf(agg[node * 64 + k] / cnt + cbias[k], 0.0f);
        hL[n][k] = h[node * 64 + k];
    }
    __syncthreads();
    {
        int j = t;  // 0..191
        float ax[8], ah[8];
#pragma unroll
        for (int n = 0; n < 8; n++) { ax[n] = 0.f; ah[n] = 0.f; }
        const float4* wi = (const float4*)(wih + j * 64);
        const float4* wh = (const float4*)(whh + j * 64);
#pragma unroll 4
        for (int k4 = 0; k4 < 16; k4++) {
            float4 wiv = wi[k4], whv = wh[k4];
#pragma unroll
            for (int n = 0; n < 8; n++) {
                ax[n] += dot4(wiv, *(const float4*)&mL[n][k4 * 4]);
                ah[n] += dot4(whv, *(const float4*)&hL[n][k4 * 4]);
            }
        }
        float bi = bih[j], bh = bhh[j];
#pragma unroll
        for (int n = 0; n < 8; n++) { gxL[n][j] = ax[n] + bi; ghL[n][j] = ah[n] + bh; }
    }
    __syncthreads();
    for (int idx = t; idx < 512; idx += 192) {
        int n = idx >> 6, k = idx & 63;
        int node = nb + n;
        float r = sigmoidf_(gxL[n][k] + ghL[n][k]);
        float zz = sigmoidf_(gxL[n][64 + k] + ghL[n][64 + k]);
        float nn = tanhf(gxL[n][128 + k] + r * ghL[n][128 + k]);
        h[node * 64 + k] = (1.0f - zz) * nn + zz * hL[n][k];
    }
}

// ---------------- Set2Set prep ----------------
__global__ void prep_wc_kernel(const float* __restrict__ wih, const float* __restrict__ whh,
                               const float* __restrict__ bih, const float* __restrict__ bhh,
                               float* __restrict__ wc, float* __restrict__ bsum) {
    int id = blockIdx.x * 256 + threadIdx.x;
    if (id < 16384) {
        int j = id >> 6, k = id & 63;
        wc[id] = wih[j * 128 + k] + whh[id];
    }
    if (id < 256) bsum[id] = bih[id] + bhh[id];
}

// c_out[n][j] = sum_k out[n][k] * lstm_w_ih[j][64+k]
__global__ __launch_bounds__(256) void cout_kernel(const float* __restrict__ h,
                                                   const float* __restrict__ wih,
                                                   float* __restrict__ cout, int N) {
    int t = threadIdx.x, nb = blockIdx.x * 8;
    __shared__ __align__(16) float oL[8][64];
    for (int idx = t; idx < 512; idx += 256) {
        int n = idx >> 6, k = idx & 63;
        oL[n][k] = h[(nb + n) * 64 + k];
    }
    __syncthreads();
    int j = t;
    float acc[8];
#pragma unroll
    for (int n = 0; n < 8; n++) acc[n] = 0.f;
    const float* wr = wih + j * 128 + 64;
#pragma unroll 4
    for (int k4 = 0; k4 < 16; k4++) {
        float4 w4 = *(const float4*)&wr[k4 * 4];
#pragma unroll
        for (int n = 0; n < 8; n++) acc[n] += dot4(w4, *(const float4*)&oL[n][k4 * 4]);
    }
#pragma unroll
    for (int n = 0; n < 8; n++) cout[(size_t)(nb + n) * 256 + j] = acc[n];
}

// LSTM step 1: all inputs zero -> g = b_ih + b_hh
__global__ void lstm_init_kernel(const float* __restrict__ bsum, float* __restrict__ hl,
                                 float* __restrict__ cl, int N) {
    int id = blockIdx.x * 256 + threadIdx.x;
    if (id >= N * 64) return;
    int j = id & 63;
    float gi = bsum[j], gg = bsum[128 + j], go = bsum[192 + j];
    float c = sigmoidf_(gi) * tanhf(gg);
    cl[id] = c;
    hl[id] = sigmoidf_(go) * tanhf(c);
}

// LSTM steps 2,3: g = hl @ Wc.T + c_out + bsum
__global__ __launch_bounds__(256) void lstm_step_kernel(const float* __restrict__ wc,
                                                        const float* __restrict__ bsum,
                                                        const float* __restrict__ cout,
                                                        float* __restrict__ hl,
                                                        float* __restrict__ cl, int N) {
    int t = threadIdx.x, nb = blockIdx.x * 8;
    __shared__ __align__(16) float hlL[8][64];
    __shared__ float gL[8][256];
    for (int idx = t; idx < 512; idx += 256) {
        int n = idx >> 6, k = idx & 63;
        hlL[n][k] = hl[(nb + n) * 64 + k];
    }
    __syncthreads();
    {
        int j = t;
        float acc[8];
#pragma unroll
        for (int n = 0; n < 8; n++) acc[n] = 0.f;
        const float4* w4p = (const float4*)(wc + j * 64);
#pragma unroll 4
        for (int k4 = 0; k4 < 16; k4++) {
            float4 w4 = w4p[k4];
#pragma unroll
            for (int n = 0; n < 8; n++) acc[n] += dot4(w4, *(const float4*)&hlL[n][k4 * 4]);
        }
        float bs = bsum[j];
#pragma unroll
        for (int n = 0; n < 8; n++) gL[n][j] = acc[n] + cout[(size_t)(nb + n) * 256 + j] + bs;
    }
    __syncthreads();
    for (int idx = t; idx < 512; idx += 256) {
        int n = idx >> 6, k = idx & 63;
        int node = nb + n;
        float gi = gL[n][k], gf = gL[n][64 + k], gg = gL[n][128 + k], go = gL[n][192 + k];
        float c = sigmoidf_(gf) * cl[node * 64 + k] + sigmoidf_(gi) * tanhf(gg);
        cl[node * 64 + k] = c;
        hl[node * 64 + k] = sigmoidf_(go) * tanhf(c);
    }
}

// ---------------- head: 4 pairs/block, wave per pair ----------------
__global__ __launch_bounds__(256) void head_kernel(
    const float* __restrict__ h, const float* __restrict__ hl, const int* __restrict__ ti,
    const int* __restrict__ tc, const float* __restrict__ w1, const float* __restrict__ b1,
    const float* __restrict__ g1, const float* __restrict__ bn1, const float* __restrict__ w2,
    const float* __restrict__ b2, float* __restrict__ out, int P) {
    int t = threadIdx.x;
    int pb = blockIdx.x * 4;
    int pl = t >> 6, j = t & 63;
    __shared__ __align__(16) float st[4][4][64];  // [arr: oa0,oa1,ha0,ha1][pair][k]
    for (int idx = t; idx < 1024; idx += 256) {
        int arr = idx >> 8, p = (idx >> 6) & 3, k = idx & 63;
        int pair = pb + p;
        int a0 = ti[pair], a1 = ti[P + pair];
        float v;
        if (arr == 0) v = h[a0 * 64 + k];
        else if (arr == 1) v = h[a1 * 64 + k];
        else if (arr == 2) v = hl[a0 * 64 + k];
        else v = hl[a1 * 64 + k];
        st[arr][p][k] = v;
    }
    __syncthreads();
    int pair = pb + pl;
    float acc = b1[j];
    const float4* w = (const float4*)(w1 + (size_t)j * 384);
    // cat segments -> staged array: [oa0, oa1, ha0, oa0, ha1, oa1]
    const int segarr[6] = {0, 1, 2, 0, 3, 1};
#pragma unroll
    for (int s = 0; s < 6; s++) {
        int arr = segarr[s];
#pragma unroll
        for (int k4 = 0; k4 < 16; k4++)
            acc += dot4(w[s * 16 + k4], *(const float4*)&st[arr][pl][k4 * 4]);
    }
    float s1 = acc, s2v = acc * acc;
#pragma unroll
    for (int m = 32; m >= 1; m >>= 1) { s1 += __shfl_xor(s1, m); s2v += __shfl_xor(s2v, m); }
    float mu = s1 * (1.0f / 64.0f);
    float var = fmaxf(s2v * (1.0f / 64.0f) - mu * mu, 0.0f);
    float p1 = fmaxf((acc - mu) * rsqrtf(var + EPS_LN) * g1[j] + bn1[j], 0.0f);
    int cls = tc[pair];
    float part = p1 * w2[cls * 64 + j];
#pragma unroll
    for (int m = 32; m >= 1; m >>= 1) part += __shfl_xor(part, m);
    if (j == 0) out[pair] = part + b2[cls];
}

extern "C" void kernel_launch(void* const* d_in, const int* in_sizes, int n_in,
                              void* d_out, int out_size, void* d_ws, size_t ws_size,
                              hipStream_t stream) {
    const float* x = (const float*)d_in[0];
    const float* edge_attr = (const float*)d_in[1];
    const float* lin0_w = (const float*)d_in[2];
    const float* lin0_b = (const float*)d_in[3];
    const float* enn_w1 = (const float*)d_in[4];
    const float* enn_b1 = (const float*)d_in[5];
    const float* enn_g1 = (const float*)d_in[6];
    const float* enn_b1n = (const float*)d_in[7];
    const float* enn_w2 = (const float*)d_in[8];
    const float* enn_b2 = (const float*)d_in[9];
    const float* enn_g2 = (const float*)d_in[10];
    const float* enn_b2n = (const float*)d_in[11];
    const float* conv_bias = (const float*)d_in[12];
    const float* gru_w_ih = (const float*)d_in[13];
    const float* gru_w_hh = (const float*)d_in[14];
    const float* gru_b_ih = (const float*)d_in[15];
    const float* gru_b_hh = (const float*)d_in[16];
    const float* lstm_w_ih = (const float*)d_in[17];
    const float* lstm_w_hh = (const float*)d_in[18];
    const float* lstm_b_ih = (const float*)d_in[19];
    const float* lstm_b_hh = (const float*)d_in[20];
    const float* lin1_w = (const float*)d_in[21];
    const float* lin1_b = (const float*)d_in[22];
    const float* lin1_g = (const float*)d_in[23];
    const float* lin1_bn = (const float*)d_in[24];
    const float* lin2_w = (const float*)d_in[25];
    const float* lin2_b = (const float*)d_in[26];
    const int* edge_index = (const int*)d_in[27];
    const int* target_index = (const int*)d_in[28];
    const int* target_class = (const int*)d_in[29];

    const int N = in_sizes[0] / 16;
    const int E = in_sizes[27] / 2;
    const int P = in_sizes[29];

    // workspace carve
    size_t off = 0;
    auto carve = [&](size_t bytes) {
        void* p = (char*)d_ws + off;
        off += (bytes + 255) & ~(size_t)255;
        return p;
    };
    unsigned short* zbuf = (unsigned short*)carve((size_t)E * 4096 * 2);  // z then ew (bf16)
    unsigned short* e1h = (unsigned short*)carve((size_t)E * 128 * 2);
    unsigned short* e1l = (unsigned short*)carve((size_t)E * 128 * 2);
    unsigned short* w2b = (unsigned short*)carve((size_t)4096 * 128 * 2);
    float* hbuf = (float*)carve((size_t)N * 64 * 4);
    float* agg = (float*)carve((size_t)N * 64 * 4);
    float* counts = (float*)carve((size_t)N * 4);
    float* hl = (float*)carve((size_t)N * 64 * 4);
    float* cl = (float*)carve((size_t)N * 64 * 4);
    float* cout_b = (float*)carve((size_t)N * 256 * 4);
    float* wc = (float*)carve((size_t)256 * 64 * 4);
    float* bsum = (float*)carve((size_t)256 * 4);
    (void)ws_size;

    hipMemsetAsync(counts, 0, (size_t)N * 4, stream);
    lin0_kernel<<<(N * 64 + 255) / 256, 256, 0, stream>>>(x, lin0_w, lin0_b, hbuf, N);
    count_kernel<<<(E + 255) / 256, 256, 0, stream>>>(edge_index, counts, E);
    w2cvt_kernel<<<(4096 * 128 + 255) / 256, 256, 0, stream>>>(enn_w2, w2b, 4096 * 128);
    edge_nn1_kernel<<<E, 128, 0, stream>>>(edge_attr, enn_w1, enn_b1, enn_g1, enn_b1n, e1h, e1l, E);
    {
        dim3 g((E + 63) / 64, 32);
        zgemm_mfma<<<g, 256, 0, stream>>>(e1h, e1l, w2b, enn_b2, zbuf, E);
    }
    ln_ew_kernel<<<E, 256, 0, stream>>>(zbuf, enn_g2, enn_b2n);

    for (int it = 0; it < 3; it++) {
        hipMemsetAsync(agg, 0, (size_t)N * 64 * 4, stream);
        msg_kernel<<<E / 4, 256, 0, stream>>>(zbuf, hbuf, edge_index, agg, E);
        gru_kernel<<<N / 8, 192, 0, stream>>>(agg, counts, conv_bias, gru_w_ih, gru_w_hh,
                                              gru_b_ih, gru_b_hh, hbuf, N);
    }

    prep_wc_kernel<<<64, 256, 0, stream>>>(lstm_w_ih, lstm_w_hh, lstm_b_ih, lstm_b_hh, wc, bsum);
    cout_kernel<<<N / 8, 256, 0, stream>>>(hbuf, lstm_w_ih, cout_b, N);
    lstm_init_kernel<<<(N * 64 + 255) / 256, 256, 0, stream>>>(bsum, hl, cl, N);
    lstm_step_kernel<<<N / 8, 256, 0, stream>>>(wc, bsum, cout_b, hl, cl, N);
    lstm_step_kernel<<<N / 8, 256, 0, stream>>>(wc, bsum, cout_b, hl, cl, N);

    head_kernel<<<P / 4, 256, 0, stream>>>(hbuf, hl, target_index, target_class, lin1_w, lin1_b,
                                           lin1_g, lin1_bn, lin2_w, lin2_b, (float*)d_out, P);
}